// Round 6
// baseline (1947.233 us; speedup 1.0000x reference)
//
#include <hip/hip_runtime.h>

// LSTM: B=512, T=1024, D=64, H=128, gates=4H=512, fc head H->64->1.
// 256 blocks (1/CU) x 512 threads, 2 batch rows/block.
//
// ROOT CAUSE (rounds 1-5): the compiler SINKS loop-invariant weight loads
// into the t-loop (remat instead of keeping 48-96 VGPRs live): VGPR_Count
// was always < weights+working (128/104/60/104) with WRITE_SIZE=8KB (no
// spill) -> ~96 global loads/thread/step re-streamed from L2 = ~7000
// cyc/step at the per-CU L2 ceiling. Fix: pin every weight register with
// an empty asm volatile ("+v") after the one-time load -- asm-defined
// values cannot be rematerialized. launch_bounds(512,1) = 512-VGPR budget.
//
// Thread (u = tid>>2, e = (tid>>1)&1, q = tid&1):
//   owns gate pair e ? {u+256 (g), u+384 (o)} : {u (i), u+128 (f)}
//   for K-half q of concat [h(128)|x(64)], BOTH batch rows.
//   96 pinned weight VGPRs; 192 asm v_dot2_f32_f16/step; 24 b128 LDS reads.
// Quad reduce on the VALU via DPP: xor1 (q) completes K; xor2 (e) swaps
// gate pairs; each lane applies the full cell for both rows (c dup x4).
// One barrier per step.

#define TT 1024
#define DD 64
#define HH 128
#define KK 192   // [h(128) | x(64)]

__device__ __forceinline__ float dot2u(unsigned a, unsigned b, float c) {
    asm("v_dot2_f32_f16 %0, %1, %2, %0" : "+v"(c) : "v"(a), "v"(b));
    return c;
}

__device__ __forceinline__ void pin(unsigned& x) {
    asm volatile("" : "+v"(x));
}
__device__ __forceinline__ void pinf(float& x) {
    asm volatile("" : "+v"(x));
}

// quad_perm [1,0,3,2] = 0xB1 (swap bit0=q), [2,3,0,1] = 0x4E (swap bit1=e)
__device__ __forceinline__ float dpp_add_xor1(float x) {
    int y = __builtin_amdgcn_update_dpp(0, __builtin_bit_cast(int, x),
                                        0xB1, 0xF, 0xF, true);
    return x + __builtin_bit_cast(float, y);
}
__device__ __forceinline__ float dpp_mov_xor2(float x) {
    int y = __builtin_amdgcn_update_dpp(0, __builtin_bit_cast(int, x),
                                        0x4E, 0xF, 0xF, true);
    return __builtin_bit_cast(float, y);
}

__device__ __forceinline__ float sigm(float x) {
    return 1.f / (1.f + __expf(-x));
}
__device__ __forceinline__ float tanh_f(float x) {
    return 1.f - 2.f / (__expf(2.f * x) + 1.f);
}

// packed-f16 pair of concat row [W_hh(128) | W_ih(64)] for gate `gate`, even k
__device__ __forceinline__ unsigned wld(const float* __restrict__ Whh,
                                        const float* __restrict__ Wih,
                                        int gate, int k) {
    float2 f;
    if (k < HH) f = *reinterpret_cast<const float2*>(Whh + gate * HH + k);
    else        f = *reinterpret_cast<const float2*>(Wih + gate * DD + (k - HH));
    _Float16 lo = (_Float16)f.x, hi = (_Float16)f.y;
    return (unsigned)__builtin_bit_cast(unsigned short, lo) |
           ((unsigned)__builtin_bit_cast(unsigned short, hi) << 16);
}

__global__ __launch_bounds__(512, 1)
void lstm_fused_kernel(const float* __restrict__ x_seq,
                       const float* __restrict__ W_ih,
                       const float* __restrict__ W_hh,
                       const float* __restrict__ b_ih,
                       const float* __restrict__ b_hh,
                       const float* __restrict__ W1v,
                       const float* __restrict__ b1v,
                       const float* __restrict__ W2v,
                       const float* __restrict__ b2v,
                       float* __restrict__ out)
{
    const int tid = threadIdx.x;
    const int q   = tid & 1;          // K-half
    const int e   = (tid >> 1) & 1;   // gate pair: 0 -> (i,f), 1 -> (g,o)
    const int u   = tid >> 2;         // hidden column 0..127
    const int b0  = blockIdx.x * 2;

    __shared__ __align__(16) _Float16 hx[2][2][KK];  // [buf][row][h|x]

    // ---- weights: 2 gates x 96 f16 (K-half) = 96 VGPRs, PINNED ----
    const int g0 = u + e * 256;         // i or g
    const int g1 = u + 128 + e * 256;   // f or o
    const int kb = q * 96;
    unsigned w0[48], w1[48];
#pragma unroll
    for (int j = 0; j < 48; ++j) {
        w0[j] = wld(W_hh, W_ih, g0, kb + 2 * j);
        w1[j] = wld(W_hh, W_ih, g1, kb + 2 * j);
    }
#pragma unroll
    for (int j = 0; j < 48; ++j) { pin(w0[j]); pin(w1[j]); }

    float bI = b_ih[u]       + b_hh[u];
    float bF = b_ih[u + 128] + b_hh[u + 128];
    float bG = b_ih[u + 256] + b_hh[u + 256];
    float bO = b_ih[u + 384] + b_hh[u + 384];
    pinf(bI); pinf(bF); pinf(bG); pinf(bO);

    // ---- init: h=0, x(0) into buffer 0 ----
    if (tid < 256) hx[0][tid >> 7][tid & 127] = (_Float16)0.f;
    if (tid < 128) {
        const int r = tid >> 6, k = tid & 63;
        hx[0][r][HH + k] = (_Float16)x_seq[((b0 + r) * TT + 0) * DD + k];
    }
    float c0 = 0.f, c1 = 0.f;  // both rows' c, duplicated across quad lanes

    // x-prefetch role: one lane per quad (q==1 && e==1), quad index u
    const bool is_pre = (q == 1) && (e == 1);
    const int  xr = u & 1, xk = u >> 1;
    __syncthreads();

    for (int t = 0; t < TT; ++t) {
        const int cur = t & 1, nxt = cur ^ 1;

        // issue next-x load early; latency hides under the dot2 block
        float xpre = 0.f;
        const bool pre = is_pre && (t + 1 < TT);
        if (pre) xpre = x_seq[((b0 + xr) * TT + (t + 1)) * DD + xk];

        const uint4* s0 = reinterpret_cast<const uint4*>(&hx[cur][0][0]) + q * 12;
        const uint4* s1 = reinterpret_cast<const uint4*>(&hx[cur][1][0]) + q * 12;

        // a<gate><row>: 4 accumulator chains, 192 dot2
        float a00 = 0.f, a01 = 0.f, a10 = 0.f, a11 = 0.f;
#pragma unroll
        for (int j = 0; j < 12; ++j) {
            const uint4 v0 = s0[j];
            const uint4 v1 = s1[j];
            a00 = dot2u(w0[4 * j + 0], v0.x, a00);
            a01 = dot2u(w0[4 * j + 0], v1.x, a01);
            a10 = dot2u(w1[4 * j + 0], v0.x, a10);
            a11 = dot2u(w1[4 * j + 0], v1.x, a11);
            a00 = dot2u(w0[4 * j + 1], v0.y, a00);
            a01 = dot2u(w0[4 * j + 1], v1.y, a01);
            a10 = dot2u(w1[4 * j + 1], v0.y, a10);
            a11 = dot2u(w1[4 * j + 1], v1.y, a11);
            a00 = dot2u(w0[4 * j + 2], v0.z, a00);
            a01 = dot2u(w0[4 * j + 2], v1.z, a01);
            a10 = dot2u(w1[4 * j + 2], v0.z, a10);
            a11 = dot2u(w1[4 * j + 2], v1.z, a11);
            a00 = dot2u(w0[4 * j + 3], v0.w, a00);
            a01 = dot2u(w0[4 * j + 3], v1.w, a01);
            a10 = dot2u(w1[4 * j + 3], v0.w, a10);
            a11 = dot2u(w1[4 * j + 3], v1.w, a11);
        }

        // ---- quad reduction, all on the VALU (DPP) ----
        a00 = dpp_add_xor1(a00);  // complete K across q
        a01 = dpp_add_xor1(a01);
        a10 = dpp_add_xor1(a10);
        a11 = dpp_add_xor1(a11);
        const float o00 = dpp_mov_xor2(a00);  // fetch other gate pair
        const float o01 = dpp_mov_xor2(a01);
        const float o10 = dpp_mov_xor2(a10);
        const float o11 = dpp_mov_xor2(a11);

        // e=0: own=(i,f), oth=(g,o); e=1: own=(g,o), oth=(i,f)
        const float gi0 = (e ? o00 : a00) + bI;
        const float gi1 = (e ? o01 : a01) + bI;
        const float gf0 = (e ? o10 : a10) + bF;
        const float gf1 = (e ? o11 : a11) + bF;
        const float gg0 = (e ? a00 : o00) + bG;
        const float gg1 = (e ? a01 : o01) + bG;
        const float go0 = (e ? a10 : o10) + bO;
        const float go1 = (e ? a11 : o11) + bO;

        // ---- cell, both rows, duplicated across the quad ----
        c0 = sigm(gf0) * c0 + sigm(gi0) * tanh_f(gg0);
        c1 = sigm(gf1) * c1 + sigm(gi1) * tanh_f(gg1);
        const float h0n = sigm(go0) * tanh_f(c0);
        const float h1n = sigm(go1) * tanh_f(c1);

        // one lane per (row,u) writes h'; prefetch lane writes x'
        if (e == 0) hx[nxt][q][u] = (_Float16)(q ? h1n : h0n);
        if (pre)    hx[nxt][xr][HH + xk] = (_Float16)xpre;
        __syncthreads();
    }

    // ---- fused head: z = relu(h @ W1^T + b1); y = z @ W2^T + b2 ----
    // final h is in hx[0] (TT even). wave 0 -> row 0, wave 1 -> row 1.
    if (tid < 128) {
        const int r = tid >> 6, j = tid & 63;
        float z = b1v[j];
        const float* w1 = W1v + j * HH;
#pragma unroll 16
        for (int k = 0; k < HH; ++k)
            z = fmaf(w1[k], (float)hx[0][r][k], z);
        z = fmaxf(z, 0.f) * W2v[j];
#pragma unroll
        for (int off = 32; off; off >>= 1)
            z += __shfl_down(z, off, 64);
        if (j == 0) out[b0 + r] = z + b2v[0];
    }
}

extern "C" void kernel_launch(void* const* d_in, const int* in_sizes, int n_in,
                              void* d_out, int out_size, void* d_ws, size_t ws_size,
                              hipStream_t stream) {
    const float* x_seq = (const float*)d_in[0];
    const float* W_ih  = (const float*)d_in[1];
    const float* W_hh  = (const float*)d_in[2];
    const float* b_ih  = (const float*)d_in[3];
    const float* b_hh  = (const float*)d_in[4];
    const float* W1    = (const float*)d_in[5];
    const float* b1    = (const float*)d_in[6];
    const float* W2    = (const float*)d_in[7];
    const float* b2    = (const float*)d_in[8];
    float* out = (float*)d_out;

    lstm_fused_kernel<<<256, 512, 0, stream>>>(
        x_seq, W_ih, W_hh, b_ih, b_hh, W1, b1, W2, b2, out);
}

// Round 7
// 1915.899 us; speedup vs baseline: 1.0164x; 1.0164x over previous
//
#include <hip/hip_runtime.h>

// LSTM: B=512, T=1024, D=64, H=128, gates=4H=512, fc head H->64->1.
//
// Rounds 1-6 post-mortem: every VALU/dot2 design needs 48-96 per-thread
// weight VGPRs resident; the allocator refuses (VGPR_Count 60-128, weights
// re-materialized from L2 every step -> stuck at 1.3-2.3 ms). This version
// switches to MFMA so the weights live as B-fragments (48 VGPRs, asm-pinned,
// consumed directly by v_mfma).
//
// 32 blocks x 1024 threads (16 waves). Block owns 16 batch rows.
// Per step: gates[16,512] = [h|x][16,192] @ W^T[192,512] via
// v_mfma_f32_16x16x32_f16: wave w owns gates [32w,32w+32) = 2 N-tiles,
// 6 K-tiles -> 12 MFMA/wave/step. A-frags: 6 ds_read_b128 from padded f16
// LDS rows (stride 400B -> even bank coverage). D layout (m89-verified):
// m=(lane>>4)*4+reg, n=lane&15 -> gl[16][516] f32 (stride 516: 2-way max).
// Cell: wave w = batch row w, lane handles u=2*lane,2*lane+1, c in regs.
// x(t+1) prefetched during MFMA phase. 2 barriers/step.

#define TT 1024
#define DD 64
#define HH 128
#define KK 192          // [h(128) | x(64)]
#define ROWS 16         // batch rows per block
#define PROW 200        // hx row stride in f16 (192 + 8 pad = 400 B)
#define GLS 516         // gl row stride in f32 (2064 B)

typedef _Float16 f16x8 __attribute__((ext_vector_type(8)));
typedef float f32x4 __attribute__((ext_vector_type(4)));

__device__ __forceinline__ float sigm(float x) {
    return 1.f / (1.f + __expf(-x));
}
__device__ __forceinline__ float tanh_f(float x) {
    return 1.f - 2.f / (__expf(2.f * x) + 1.f);
}

__global__ __launch_bounds__(1024, 1)
void lstm_mfma_kernel(const float* __restrict__ x_seq,
                      const float* __restrict__ W_ih,
                      const float* __restrict__ W_hh,
                      const float* __restrict__ b_ih,
                      const float* __restrict__ b_hh,
                      const float* __restrict__ W1v,
                      const float* __restrict__ b1v,
                      const float* __restrict__ W2v,
                      const float* __restrict__ b2v,
                      float* __restrict__ out)
{
    const int tid  = threadIdx.x;
    const int lane = tid & 63;
    const int w    = tid >> 6;        // wave 0..15
    const int p    = lane >> 4;       // k-group 0..3
    const int cc   = lane & 15;       // col (B/D) or row (A) within tile
    const int b0   = blockIdx.x * ROWS;

    __shared__ __align__(16) _Float16 hx[ROWS][PROW];  // [row][h(128)|x(64)]
    __shared__ __align__(16) float    gl[ROWS][GLS];   // [row][gate]

    // ---- B-fragments: wave w owns gates [32w, 32w+32), K-tiles 0..5 ----
    // frag(nt,g): lane holds W^T[k=32g+8p+j][n=32w+16nt+cc], j=0..7
    f16x8 bf[2][6];
#pragma unroll
    for (int nt = 0; nt < 2; ++nt) {
        const int gate = 32 * w + 16 * nt + cc;
#pragma unroll
        for (int g = 0; g < 6; ++g) {
            f16x8 f;
#pragma unroll
            for (int j = 0; j < 8; ++j) {
                const int k = 32 * g + 8 * p + j;
                const float v = (k < HH) ? W_hh[gate * HH + k]
                                         : W_ih[gate * DD + (k - HH)];
                f[j] = (_Float16)v;
            }
            bf[nt][g] = f;
        }
    }
#pragma unroll
    for (int nt = 0; nt < 2; ++nt)
#pragma unroll
        for (int g = 0; g < 6; ++g)
            asm volatile("" : "+v"(bf[nt][g]));

    // ---- cell-phase constants: wave w = row w, cells u0, u0+1 ----
    const int u0 = 2 * lane;
    const float bI0 = b_ih[u0]           + b_hh[u0];
    const float bI1 = b_ih[u0 + 1]       + b_hh[u0 + 1];
    const float bF0 = b_ih[u0 + 128]     + b_hh[u0 + 128];
    const float bF1 = b_ih[u0 + 129]     + b_hh[u0 + 129];
    const float bG0 = b_ih[u0 + 256]     + b_hh[u0 + 256];
    const float bG1 = b_ih[u0 + 257]     + b_hh[u0 + 257];
    const float bO0 = b_ih[u0 + 384]     + b_hh[u0 + 384];
    const float bO1 = b_ih[u0 + 385]     + b_hh[u0 + 385];
    float c0 = 0.f, c1 = 0.f;

    // ---- init: h = 0, x(0) staged ----
    hx[w][u0]     = (_Float16)0.f;
    hx[w][u0 + 1] = (_Float16)0.f;
    hx[w][HH + lane] = (_Float16)x_seq[((b0 + w) * TT + 0) * DD + lane];
    __syncthreads();

    for (int t = 0; t < TT; ++t) {
        // prefetch x(t+1): row w, elem lane (coalesced per wave)
        float xp = 0.f;
        if (t + 1 < TT)
            xp = x_seq[((b0 + w) * TT + (t + 1)) * DD + lane];

        // ---- MFMA phase: A row = cc, k-slice 32g+8p ----
        f32x4 acc0 = {0.f, 0.f, 0.f, 0.f};
        f32x4 acc1 = {0.f, 0.f, 0.f, 0.f};
#pragma unroll
        for (int g = 0; g < 6; ++g) {
            const f16x8 a =
                *reinterpret_cast<const f16x8*>(&hx[cc][32 * g + 8 * p]);
            acc0 = __builtin_amdgcn_mfma_f32_16x16x32_f16(a, bf[0][g], acc0,
                                                          0, 0, 0);
            acc1 = __builtin_amdgcn_mfma_f32_16x16x32_f16(a, bf[1][g], acc1,
                                                          0, 0, 0);
        }
        // D(m,n): m = 4p + j, n = 32w + 16nt + cc
#pragma unroll
        for (int j = 0; j < 4; ++j) {
            gl[4 * p + j][32 * w + cc]      = acc0[j];
            gl[4 * p + j][32 * w + 16 + cc] = acc1[j];
        }
        __syncthreads();

        // ---- cell: row w, cells u0 and u0+1 (c in registers) ----
        const float gi0 = gl[w][u0]           + bI0;
        const float gi1 = gl[w][u0 + 1]       + bI1;
        const float gf0 = gl[w][u0 + 128]     + bF0;
        const float gf1 = gl[w][u0 + 129]     + bF1;
        const float gg0 = gl[w][u0 + 256]     + bG0;
        const float gg1 = gl[w][u0 + 257]     + bG1;
        const float go0 = gl[w][u0 + 384]     + bO0;
        const float go1 = gl[w][u0 + 385]     + bO1;

        c0 = sigm(gf0) * c0 + sigm(gi0) * tanh_f(gg0);
        c1 = sigm(gf1) * c1 + sigm(gi1) * tanh_f(gg1);
        hx[w][u0]     = (_Float16)(sigm(go0) * tanh_f(c0));
        hx[w][u0 + 1] = (_Float16)(sigm(go1) * tanh_f(c1));
        hx[w][HH + lane] = (_Float16)xp;   // x(t+1) (garbage 0 on last iter)
        __syncthreads();
    }

    // ---- fused head: wave w = row w; lane j = hidden unit of fc1 ----
    {
        float z = b1v[lane];
        const float* w1 = W1v + lane * HH;
#pragma unroll 16
        for (int k = 0; k < HH; ++k)
            z = fmaf(w1[k], (float)hx[w][k], z);
        z = fmaxf(z, 0.f) * W2v[lane];
#pragma unroll
        for (int off = 32; off; off >>= 1)
            z += __shfl_down(z, off, 64);
        if (lane == 0) out[b0 + w] = z + b2v[0];
    }
}

extern "C" void kernel_launch(void* const* d_in, const int* in_sizes, int n_in,
                              void* d_out, int out_size, void* d_ws, size_t ws_size,
                              hipStream_t stream) {
    const float* x_seq = (const float*)d_in[0];
    const float* W_ih  = (const float*)d_in[1];
    const float* W_hh  = (const float*)d_in[2];
    const float* b_ih  = (const float*)d_in[3];
    const float* b_hh  = (const float*)d_in[4];
    const float* W1    = (const float*)d_in[5];
    const float* b1    = (const float*)d_in[6];
    const float* W2    = (const float*)d_in[7];
    const float* b2    = (const float*)d_in[8];
    float* out = (float*)d_out;

    lstm_mfma_kernel<<<32, 1024, 0, stream>>>(
        x_seq, W_ih, W_hh, b_ih, b_hh, W1, b1, W2, b2, out);
}